// Round 11
// baseline (298.001 us; speedup 1.0000x reference)
//
#include <hip/hip_runtime.h>
#include <math.h>

typedef __bf16 bf16x8 __attribute__((ext_vector_type(8)));
typedef float  f32x4  __attribute__((ext_vector_type(4)));

#define NEGB   (-1.4426950408889634e30f)   // -1e30 * log2(e)  (log2-domain mask value)
#define SCALE2 (0.18033688011112042f)      // (1/sqrt(64)) * log2(e), folded into q

template <int N> struct ic { static constexpr int value = N; };

static __device__ __forceinline__ f32x4 mfma16(bf16x8 a, bf16x8 b, f32x4 c) {
    return __builtin_amdgcn_mfma_f32_16x16x32_bf16(a, b, c, 0, 0, 0);
}

// async global->LDS, 16B per lane; lds dst = uniform base + lane*16
static __device__ __forceinline__ void load_lds16(const void* g, void* l) {
    __builtin_amdgcn_global_load_lds(
        (const __attribute__((address_space(1))) unsigned int*)g,
        (__attribute__((address_space(3))) unsigned int*)l, 16, 0, 0);
}

// DPP row_ror (within 16-lane rows) — VALU-only cross-lane, no DS pipe
template <int CTRL>
static __device__ __forceinline__ float dppf(float x) {
    int xi = __builtin_bit_cast(int, x);
    int r = __builtin_amdgcn_update_dpp(xi, xi, CTRL, 0xf, 0xf, false);
    return __builtin_bit_cast(float, r);
}
static __device__ __forceinline__ float rowmax16(float x) {
    x = fmaxf(x, dppf<0x128>(x));
    x = fmaxf(x, dppf<0x124>(x));
    x = fmaxf(x, dppf<0x122>(x));
    x = fmaxf(x, dppf<0x121>(x));
    return x;
}
static __device__ __forceinline__ float rowsum16(float x) {
    x += dppf<0x128>(x);
    x += dppf<0x124>(x);
    x += dppf<0x122>(x);
    x += dppf<0x121>(x);
    return x;
}

// ---------------- prep (r10, exact): mask -> bitmask, W -> hi/lo bf16 fragment order ------
__global__ void prep_kernel(const int* __restrict__ mask,
                            const float* __restrict__ Wq, const float* __restrict__ Wk,
                            const float* __restrict__ Wv,
                            unsigned long long* __restrict__ mbits,
                            __bf16* __restrict__ Whi_t, __bf16* __restrict__ Wlo_t)
{
    const int tid = threadIdx.x;
    if (blockIdx.x < 1024) {
        const int row = blockIdx.x, wave = tid >> 6, lane = tid & 63;
        #pragma unroll
        for (int i = 0; i < 4; ++i) {
            int word = wave * 4 + i;
            int m = mask[row * 1024 + word * 64 + lane];
            unsigned long long b = __ballot(m != 0);
            if (lane == 0) mbits[row * 16 + word] = b;
        }
    } else {
        int idx = (blockIdx.x - 1024) * 256 + tid;          // 0..49151
        int lane = idx & 63, t = (idx >> 6) & 3, kc = (idx >> 8) & 7;
        int head = (idx >> 11) & 7, mat = idx >> 14;
        int quad = lane >> 4, ln = lane & 15;
        const float* W = (mat == 0 ? Wq : (mat == 1 ? Wk : Wv)) + head * 16384;
        bf16x8 hi, lo;
        #pragma unroll
        for (int j = 0; j < 8; ++j) {
            float w = W[(kc * 32 + quad * 8 + j) * 64 + t * 16 + ln];
            __bf16 hh = (__bf16)w;
            hi[j] = hh;
            lo[j] = (__bf16)(w - (float)hh);
        }
        *(bf16x8*)(Whi_t + (size_t)idx * 8) = hi;
        *(bf16x8*)(Wlo_t + (size_t)idx * 8) = lo;
    }
}

// ---------------- projKV (r10, exact): K+V fused, W staged in LDS in TWO kc-halves --------
__global__ __launch_bounds__(256) void projkv_kernel(
    const float* __restrict__ X,
    const __bf16* __restrict__ Whi_t, const __bf16* __restrict__ Wlo_t,
    unsigned char* __restrict__ khi_g, unsigned char* __restrict__ klo_g,
    unsigned char* __restrict__ vT_g)
{
    const int head = blockIdx.x, rt = blockIdx.y;
    const int tid = threadIdx.x, wave = tid >> 6, lane = tid & 63;
    const int quad = lane >> 4, ln = lane & 15;

    __shared__ __align__(16) unsigned char WL[49152];   // [KhiK 16K][KloK 16K][VhiV 16K] per half

    const unsigned char* WhiK = (const unsigned char*)(Whi_t + ((size_t)(8 + head) * 2048) * 8);
    const unsigned char* WloK = (const unsigned char*)(Wlo_t + ((size_t)(8 + head) * 2048) * 8);
    const unsigned char* WhiV = (const unsigned char*)(Whi_t + ((size_t)(16 + head) * 2048) * 8);

    auto stageHalf = [&](int h) {
        #pragma unroll
        for (int r = 0; r < 4; ++r) {
            int seg = r * 4 + wave;                     // 0..15, wave-uniform per wave
            int gb = h * 16384 + seg * 1024 + lane * 16;
            load_lds16(WhiK + gb, WL + seg * 1024);
            load_lds16(WloK + gb, WL + 16384 + seg * 1024);
            load_lds16(WhiV + gb, WL + 32768 + seg * 1024);
        }
    };

    stageHalf(0);

    const float* xr = X + ((size_t)(rt * 64 + wave * 16 + ln)) * 256;
    bf16x8 ahi[8], alo[8];
    #pragma unroll
    for (int kc = 0; kc < 8; ++kc) {
        f32x4 xa = *(const f32x4*)(xr + kc * 32 + quad * 8);
        f32x4 xb = *(const f32x4*)(xr + kc * 32 + quad * 8 + 4);
        #pragma unroll
        for (int j = 0; j < 4; ++j) {
            __bf16 h0 = (__bf16)xa[j]; ahi[kc][j] = h0; alo[kc][j] = (__bf16)(xa[j] - (float)h0);
            __bf16 h1 = (__bf16)xb[j]; ahi[kc][4 + j] = h1; alo[kc][4 + j] = (__bf16)(xb[j] - (float)h1);
        }
    }

    f32x4 kacc[4], vacc[4];
    #pragma unroll
    for (int t = 0; t < 4; ++t) { kacc[t] = (f32x4){0.f,0.f,0.f,0.f}; vacc[t] = kacc[t]; }

    #pragma unroll
    for (int h = 0; h < 2; ++h) {
        __syncthreads();
        #pragma unroll
        for (int kcl = 0; kcl < 4; ++kcl) {
            int kc = h * 4 + kcl;
            #pragma unroll
            for (int t = 0; t < 4; ++t) {
                int fo = ((kcl * 4 + t) * 64 + lane) * 16;
                bf16x8 bhiK = *(const bf16x8*)(WL + fo);
                bf16x8 bloK = *(const bf16x8*)(WL + 16384 + fo);
                bf16x8 bhiV = *(const bf16x8*)(WL + 32768 + fo);
                kacc[t] = mfma16(ahi[kc], bhiK, kacc[t]);
                kacc[t] = mfma16(alo[kc], bhiK, kacc[t]);
                kacc[t] = mfma16(ahi[kc], bloK, kacc[t]);
                vacc[t] = mfma16(ahi[kc], bhiV, vacc[t]);
            }
        }
        __syncthreads();
        if (h == 0) stageHalf(1);
    }

    #pragma unroll
    for (int t = 0; t < 4; ++t) {
        #pragma unroll
        for (int r = 0; r < 4; ++r) {
            {   // K: hi/lo planes
                float val = kacc[t][r];
                __bf16 hh = (__bf16)val;
                __bf16 ll = (__bf16)(val - (float)hh);
                int row = wave * 16 + quad * 4 + r;
                int lc = t * 2 + (ln >> 3);
                int sc = lc ^ (row & 7);
                int off = (row * 8 + sc) * 16 + (ln & 7) * 2;
                *(__bf16*)(WL + off) = hh;
                *(__bf16*)(WL + 8192 + off) = ll;
            }
            {   // V transposed [dv][m]
                int dvrow = t * 16 + ln;
                int m = wave * 16 + quad * 4 + r;
                int lc = m >> 3;
                int sc = lc ^ (ln & 7);
                int off = (dvrow * 8 + sc) * 16 + (m & 7) * 2;
                *(__bf16*)(WL + 16384 + off) = (__bf16)vacc[t][r];
            }
        }
    }
    __syncthreads();

    const int bh = (rt >> 4) * 8 + head;
    const int mt = rt & 15;
    const size_t tb = (size_t)(bh * 16 + mt) * 8192;
    #pragma unroll
    for (int i = 0; i < 2; ++i) {
        int c = (i * 256 + tid) * 16;
        *(uint4*)(khi_g + tb + c) = *(const uint4*)(WL + c);
        *(uint4*)(klo_g + tb + c) = *(const uint4*)(WL + 8192 + c);
        *(uint4*)(vT_g  + tb + c) = *(const uint4*)(WL + 16384 + c);
    }
}

// ---------------- attn v11: r10 structure, liveness-trimmed, 3 waves/SIMD target ----------
// block = 256 thr (4 waves x 32 q-rows), BM=128, grid (128 bh FAST, 8 qt SLOW)
__global__ __launch_bounds__(256, 3) void attn_kernel(
    const float* __restrict__ X,
    const __bf16* __restrict__ Whi_t, const __bf16* __restrict__ Wlo_t,
    const unsigned char* __restrict__ khi_g, const unsigned char* __restrict__ klo_g,
    const unsigned char* __restrict__ vT_g, const unsigned long long* __restrict__ mbits,
    float* __restrict__ out)
{
    const int qt = blockIdx.y;     // 0..7
    const int bh = blockIdx.x;     // 0..127
    const int b = bh >> 3, head = bh & 7;
    const int tid = threadIdx.x, wave = tid >> 6, lane = tid & 63;
    const int quad = lane >> 4, ln = lane & 15;

    __shared__ __align__(16) unsigned char lds[49152];
    // buffers at 0 and 24576: [khi 8K][klo 8K][v 8K]; P overlays dead khi+klo (4 KB/wave)

    // ===================== Phase Q: q' = (X Wq) * SCALE2, 3-term split =====================
    f32x4 qacc[2][4];
    #pragma unroll
    for (int rg = 0; rg < 2; ++rg)
        #pragma unroll
        for (int t = 0; t < 4; ++t) qacc[rg][t] = (f32x4){0.f, 0.f, 0.f, 0.f};

    const __bf16* WhiQ = Whi_t + (size_t)head * 2048 * 8;
    const __bf16* WloQ = Wlo_t + (size_t)head * 2048 * 8;

    #pragma unroll
    for (int kc = 0; kc < 8; ++kc) {
        bf16x8 ahi[2], alo[2];
        #pragma unroll
        for (int rg = 0; rg < 2; ++rg) {
            const float* xr = X + ((size_t)b * 1024 + qt * 128 + wave * 32 + rg * 16 + ln) * 256;
            f32x4 xa = *(const f32x4*)(xr + kc * 32 + quad * 8);
            f32x4 xb = *(const f32x4*)(xr + kc * 32 + quad * 8 + 4);
            #pragma unroll
            for (int j = 0; j < 4; ++j) {
                __bf16 h0 = (__bf16)xa[j]; ahi[rg][j] = h0; alo[rg][j] = (__bf16)(xa[j] - (float)h0);
                __bf16 h1 = (__bf16)xb[j]; ahi[rg][4 + j] = h1; alo[rg][4 + j] = (__bf16)(xb[j] - (float)h1);
            }
        }
        #pragma unroll
        for (int t = 0; t < 4; ++t) {
            size_t fo = (size_t)((kc * 4 + t) * 64 + lane) * 8;
            bf16x8 bhi = *(const bf16x8*)(WhiQ + fo);
            bf16x8 blo = *(const bf16x8*)(WloQ + fo);
            #pragma unroll
            for (int rg = 0; rg < 2; ++rg) {
                qacc[rg][t] = mfma16(ahi[rg], bhi, qacc[rg][t]);
                qacc[rg][t] = mfma16(alo[rg], bhi, qacc[rg][t]);
                qacc[rg][t] = mfma16(ahi[rg], blo, qacc[rg][t]);
            }
        }
    }

    // C-layout -> A-layout transpose via LDS (per-wave region, 32 rows x 272B)
    #pragma unroll
    for (int rg = 0; rg < 2; ++rg)
        #pragma unroll
        for (int t = 0; t < 4; ++t) {
            qacc[rg][t] *= SCALE2;
            #pragma unroll
            for (int r = 0; r < 4; ++r)
                *(float*)(lds + wave * 8704 + (rg * 16 + quad * 4 + r) * 272 + (t * 16 + ln) * 4) =
                    qacc[rg][t][r];
        }
    bf16x8 qhi[2][2], qlo[2][2];
    #pragma unroll
    for (int rg = 0; rg < 2; ++rg)
        #pragma unroll
        for (int c = 0; c < 2; ++c) {
            f32x4 a0 = *(const f32x4*)(lds + wave * 8704 + (rg * 16 + ln) * 272 + c * 128 + quad * 32);
            f32x4 a1 = *(const f32x4*)(lds + wave * 8704 + (rg * 16 + ln) * 272 + c * 128 + quad * 32 + 16);
            #pragma unroll
            for (int j = 0; j < 4; ++j) {
                __bf16 h0 = (__bf16)a0[j]; qhi[rg][c][j] = h0; qlo[rg][c][j] = (__bf16)(a0[j] - (float)h0);
                __bf16 h1 = (__bf16)a1[j]; qhi[rg][c][4 + j] = h1; qlo[rg][c][4 + j] = (__bf16)(a1[j] - (float)h1);
            }
        }
    __syncthreads();

    // ===================== Phase A: flash loop over 16 m-tiles =====================
    int addrA[4][2], addrP[2];
    #pragma unroll
    for (int t = 0; t < 4; ++t)
        #pragma unroll
        for (int c = 0; c < 2; ++c)
            addrA[t][c] = (t * 16 + ln) * 128 + (((c * 4 + quad) ^ (ln & 7)) << 4);
    #pragma unroll
    for (int c = 0; c < 2; ++c)
        addrP[c] = ln * 128 + (((c * 4 + quad) ^ (ln & 7)) << 4);

    f32x4 o[2][4];
    float mrow[2][4], lrow[2][4];
    #pragma unroll
    for (int rg = 0; rg < 2; ++rg)
        #pragma unroll
        for (int t = 0; t < 4; ++t) {
            o[rg][t] = (f32x4){0.f, 0.f, 0.f, 0.f};
            mrow[rg][t] = -INFINITY; lrow[rg][t] = 0.f;   // [rg][r]
        }

    const int qrow0 = qt * 128 + wave * 32 + quad * 4;

    auto stage = [&](int mt, int bufb) {
        const unsigned char* kb = khi_g + (size_t)(bh * 16 + mt) * 8192;
        const unsigned char* lb = klo_g + (size_t)(bh * 16 + mt) * 8192;
        const unsigned char* vb = vT_g + (size_t)(bh * 16 + mt) * 8192;
        #pragma unroll
        for (int j = 0; j < 2; ++j) {
            int ch = j * 256 + wave * 64;
            load_lds16(kb + (size_t)(ch + lane) * 16, lds + bufb + ch * 16);
            load_lds16(lb + (size_t)(ch + lane) * 16, lds + bufb + 8192 + ch * 16);
            load_lds16(vb + (size_t)(ch + lane) * 16, lds + bufb + 16384 + ch * 16);
        }
    };

    auto step = [&](auto bofc, int mt) {
        constexpr int BOFF = decltype(bofc)::value;
        if (mt < 15) stage(mt + 1, 24576 - BOFF);      // prefetch next tile into other buffer

        // ---- S = q' K^T (3-term, log2 domain) ----
        f32x4 s[2][4];
        #pragma unroll
        for (int rg = 0; rg < 2; ++rg)
            #pragma unroll
            for (int t = 0; t < 4; ++t) s[rg][t] = (f32x4){0.f, 0.f, 0.f, 0.f};
        #pragma unroll
        for (int t = 0; t < 4; ++t)
            #pragma unroll
            for (int c = 0; c < 2; ++c) {
                bf16x8 khi = *(const bf16x8*)(lds + BOFF + addrA[t][c]);
                bf16x8 klo = *(const bf16x8*)(lds + BOFF + 8192 + addrA[t][c]);
                #pragma unroll
                for (int rg = 0; rg < 2; ++rg) {
                    s[rg][t] = mfma16(qhi[rg][c], khi, s[rg][t]);
                    s[rg][t] = mfma16(qlo[rg][c], khi, s[rg][t]);
                    s[rg][t] = mfma16(qhi[rg][c], klo, s[rg][t]);
                }
            }

        // all waves done reading khi/klo -> safe to overlay P (keep prefetch in flight)
        asm volatile("s_waitcnt lgkmcnt(0)\n\ts_barrier" ::: "memory");

        // ---- mask + online softmax (DPP), per-row immediate P write + O rescale ----
        #pragma unroll
        for (int rg = 0; rg < 2; ++rg) {
            #pragma unroll
            for (int r = 0; r < 4; ++r) {
                uint2 wmv = *(const uint2*)((const unsigned char*)mbits +
                                            ((size_t)(qrow0 + rg * 16 + r) * 16 + mt) * 8);
                float sv[4];
                #pragma unroll
                for (int t = 0; t < 4; ++t) {
                    unsigned bits = (t & 2) ? wmv.y : wmv.x;
                    float bit = (float)((bits >> ((t & 1) * 16 + ln)) & 1u);
                    sv[t] = fmaf(bit, NEGB, s[rg][t][r]);
                }
                float tm = fmaxf(fmaxf(sv[0], sv[1]), fmaxf(sv[2], sv[3]));
                tm = rowmax16(tm);
                float mn = fmaxf(mrow[rg][r], tm);
                float a = __builtin_amdgcn_exp2f(mrow[rg][r] - mn);
                float p[4];
                float rs = 0.f;
                #pragma unroll
                for (int t = 0; t < 4; ++t) {
                    p[t] = __builtin_amdgcn_exp2f(sv[t] - mn);
                    rs += p[t];
                }
                // P row write (XOR-swizzled per-wave region in dead khi/klo) — overlaps sum-reduce
                const int row = quad * 4 + r;
                #pragma unroll
                for (int t = 0; t < 4; ++t) {
                    int lc16 = t * 32 + ((ln >> 3) << 4);
                    int addr = BOFF + wave * 4096 + rg * 2048 + row * 128 +
                               (lc16 ^ ((row & 7) << 4)) + ((ln & 7) << 1);
                    *(__bf16*)(lds + addr) = (__bf16)p[t];
                }
                rs = rowsum16(rs);
                lrow[rg][r] = lrow[rg][r] * a + rs;
                mrow[rg][r] = mn;
                #pragma unroll
                for (int t = 0; t < 4; ++t) o[rg][t][r] *= a;
            }
        }
        // same-wave P RAW ordering
        asm volatile("s_waitcnt lgkmcnt(0)" ::: "memory");

        // ---- O += P V ----
        #pragma unroll
        for (int c = 0; c < 2; ++c) {
            bf16x8 pa[2];
            #pragma unroll
            for (int rg = 0; rg < 2; ++rg)
                pa[rg] = *(const bf16x8*)(lds + BOFF + wave * 4096 + rg * 2048 + addrP[c]);
            #pragma unroll
            for (int t = 0; t < 4; ++t) {
                bf16x8 vb = *(const bf16x8*)(lds + BOFF + 16384 + addrA[t][c]);
                #pragma unroll
                for (int rg = 0; rg < 2; ++rg) o[rg][t] = mfma16(pa[rg], vb, o[rg][t]);
            }
        }
        __syncthreads();   // drains prefetch (vmcnt0) + P reads; next tile ready
    };

    stage(0, 0);
    __syncthreads();
    for (int mp = 0; mp < 8; ++mp) {
        step(ic<0>{}, 2 * mp);
        step(ic<24576>{}, 2 * mp + 1);
    }

    // ---- epilogue ----
    float* ob = out + (size_t)bh * 65536;
    #pragma unroll
    for (int rg = 0; rg < 2; ++rg)
        #pragma unroll
        for (int r = 0; r < 4; ++r) {
            float inv = 1.0f / lrow[rg][r];
            #pragma unroll
            for (int t = 0; t < 4; ++t)
                ob[(size_t)(qrow0 + rg * 16 + r) * 64 + t * 16 + ln] = o[rg][t][r] * inv;
        }
}

extern "C" void kernel_launch(void* const* d_in, const int* in_sizes, int n_in,
                              void* d_out, int out_size, void* d_ws, size_t ws_size,
                              hipStream_t stream) {
    const float* h    = (const float*)d_in[0];   // [16,1024,256] fp32
    const int*   mask = (const int*)d_in[1];     // [1024,1024] int32
    const float* Wq   = (const float*)d_in[2];   // [8,256,64] fp32
    const float* Wk   = (const float*)d_in[3];
    const float* Wv   = (const float*)d_in[4];
    float* out = (float*)d_out;                  // [16,8,1024,64] fp32

    unsigned char* ws = (unsigned char*)d_ws;
    unsigned char* khi_g = ws;                                   // 16 MB
    unsigned char* klo_g = ws + 16777216;                        // 16 MB
    unsigned char* vT_g  = ws + 33554432;                        // 16 MB
    __bf16* Whi_t = (__bf16*)(ws + 50331648);                    // 768 KB
    __bf16* Wlo_t = (__bf16*)(ws + 51118080);                    // 768 KB
    unsigned long long* mbits = (unsigned long long*)(ws + 51904512); // 128 KB

    prep_kernel<<<1216, 256, 0, stream>>>(mask, Wq, Wk, Wv, mbits, Whi_t, Wlo_t);
    projkv_kernel<<<dim3(8, 256), 256, 0, stream>>>(h, Whi_t, Wlo_t, khi_g, klo_g, vT_g);
    attn_kernel<<<dim3(128, 8), 256, 0, stream>>>(h, Whi_t, Wlo_t, khi_g, klo_g, vT_g, mbits, out);
}

// Round 12
// 246.620 us; speedup vs baseline: 1.2083x; 1.2083x over previous
//
#include <hip/hip_runtime.h>
#include <math.h>

typedef __bf16 bf16x8 __attribute__((ext_vector_type(8)));
typedef float  f32x4  __attribute__((ext_vector_type(4)));

#define NEGB   (-1.4426950408889634e30f)   // -1e30 * log2(e)  (log2-domain mask value)
#define SCALE2 (0.18033688011112042f)      // (1/sqrt(64)) * log2(e), folded into q

template <int N> struct ic { static constexpr int value = N; };

static __device__ __forceinline__ f32x4 mfma16(bf16x8 a, bf16x8 b, f32x4 c) {
    return __builtin_amdgcn_mfma_f32_16x16x32_bf16(a, b, c, 0, 0, 0);
}

// async global->LDS, 16B per lane; lds dst = uniform base + lane*16
static __device__ __forceinline__ void load_lds16(const void* g, void* l) {
    __builtin_amdgcn_global_load_lds(
        (const __attribute__((address_space(1))) unsigned int*)g,
        (__attribute__((address_space(3))) unsigned int*)l, 16, 0, 0);
}

// DPP row_ror (within 16-lane rows) — VALU-only cross-lane, no DS pipe
template <int CTRL>
static __device__ __forceinline__ float dppf(float x) {
    int xi = __builtin_bit_cast(int, x);
    int r = __builtin_amdgcn_update_dpp(xi, xi, CTRL, 0xf, 0xf, false);
    return __builtin_bit_cast(float, r);
}
static __device__ __forceinline__ float rowmax16(float x) {
    x = fmaxf(x, dppf<0x128>(x));
    x = fmaxf(x, dppf<0x124>(x));
    x = fmaxf(x, dppf<0x122>(x));
    x = fmaxf(x, dppf<0x121>(x));
    return x;
}
static __device__ __forceinline__ float rowsum16(float x) {
    x += dppf<0x128>(x);
    x += dppf<0x124>(x);
    x += dppf<0x122>(x);
    x += dppf<0x121>(x);
    return x;
}

// ---------------- prep v12: mask -> bitmask (128 blocks x 8 rows) + W -> hi/lo frags ------
__global__ void prep_kernel(const int* __restrict__ mask,
                            const float* __restrict__ Wq, const float* __restrict__ Wk,
                            const float* __restrict__ Wv,
                            unsigned long long* __restrict__ mbits,
                            __bf16* __restrict__ Whi_t, __bf16* __restrict__ Wlo_t)
{
    const int tid = threadIdx.x;
    if (blockIdx.x < 128) {
        const int wave = tid >> 6, lane = tid & 63;
        #pragma unroll
        for (int rr = 0; rr < 2; ++rr) {
            int row = blockIdx.x * 8 + wave * 2 + rr;
            #pragma unroll
            for (int w = 0; w < 16; ++w) {
                int m = mask[row * 1024 + w * 64 + lane];
                unsigned long long b = __ballot(m != 0);
                if (lane == 0) mbits[row * 16 + w] = b;
            }
        }
    } else {
        int idx = (blockIdx.x - 128) * 256 + tid;           // 0..49151
        int lane = idx & 63, t = (idx >> 6) & 3, kc = (idx >> 8) & 7;
        int head = (idx >> 11) & 7, mat = idx >> 14;
        int quad = lane >> 4, ln = lane & 15;
        const float* W = (mat == 0 ? Wq : (mat == 1 ? Wk : Wv)) + head * 16384;
        bf16x8 hi, lo;
        #pragma unroll
        for (int j = 0; j < 8; ++j) {
            float w = W[(kc * 32 + quad * 8 + j) * 64 + t * 16 + ln];
            __bf16 hh = (__bf16)w;
            hi[j] = hh;
            lo[j] = (__bf16)(w - (float)hh);
        }
        *(bf16x8*)(Whi_t + (size_t)idx * 8) = hi;
        *(bf16x8*)(Wlo_t + (size_t)idx * 8) = lo;
    }
}

// ---------------- projKV (r10, exact): K+V fused, W staged in LDS in TWO kc-halves --------
__global__ __launch_bounds__(256) void projkv_kernel(
    const float* __restrict__ X,
    const __bf16* __restrict__ Whi_t, const __bf16* __restrict__ Wlo_t,
    unsigned char* __restrict__ khi_g, unsigned char* __restrict__ klo_g,
    unsigned char* __restrict__ vT_g)
{
    const int head = blockIdx.x, rt = blockIdx.y;
    const int tid = threadIdx.x, wave = tid >> 6, lane = tid & 63;
    const int quad = lane >> 4, ln = lane & 15;

    __shared__ __align__(16) unsigned char WL[49152];   // [KhiK 16K][KloK 16K][VhiV 16K] per half

    const unsigned char* WhiK = (const unsigned char*)(Whi_t + ((size_t)(8 + head) * 2048) * 8);
    const unsigned char* WloK = (const unsigned char*)(Wlo_t + ((size_t)(8 + head) * 2048) * 8);
    const unsigned char* WhiV = (const unsigned char*)(Whi_t + ((size_t)(16 + head) * 2048) * 8);

    auto stageHalf = [&](int h) {
        #pragma unroll
        for (int r = 0; r < 4; ++r) {
            int seg = r * 4 + wave;                     // 0..15, wave-uniform per wave
            int gb = h * 16384 + seg * 1024 + lane * 16;
            load_lds16(WhiK + gb, WL + seg * 1024);
            load_lds16(WloK + gb, WL + 16384 + seg * 1024);
            load_lds16(WhiV + gb, WL + 32768 + seg * 1024);
        }
    };

    stageHalf(0);

    const float* xr = X + ((size_t)(rt * 64 + wave * 16 + ln)) * 256;
    bf16x8 ahi[8], alo[8];
    #pragma unroll
    for (int kc = 0; kc < 8; ++kc) {
        f32x4 xa = *(const f32x4*)(xr + kc * 32 + quad * 8);
        f32x4 xb = *(const f32x4*)(xr + kc * 32 + quad * 8 + 4);
        #pragma unroll
        for (int j = 0; j < 4; ++j) {
            __bf16 h0 = (__bf16)xa[j]; ahi[kc][j] = h0; alo[kc][j] = (__bf16)(xa[j] - (float)h0);
            __bf16 h1 = (__bf16)xb[j]; ahi[kc][4 + j] = h1; alo[kc][4 + j] = (__bf16)(xb[j] - (float)h1);
        }
    }

    f32x4 kacc[4], vacc[4];
    #pragma unroll
    for (int t = 0; t < 4; ++t) { kacc[t] = (f32x4){0.f,0.f,0.f,0.f}; vacc[t] = kacc[t]; }

    #pragma unroll
    for (int h = 0; h < 2; ++h) {
        __syncthreads();
        #pragma unroll
        for (int kcl = 0; kcl < 4; ++kcl) {
            int kc = h * 4 + kcl;
            #pragma unroll
            for (int t = 0; t < 4; ++t) {
                int fo = ((kcl * 4 + t) * 64 + lane) * 16;
                bf16x8 bhiK = *(const bf16x8*)(WL + fo);
                bf16x8 bloK = *(const bf16x8*)(WL + 16384 + fo);
                bf16x8 bhiV = *(const bf16x8*)(WL + 32768 + fo);
                kacc[t] = mfma16(ahi[kc], bhiK, kacc[t]);
                kacc[t] = mfma16(alo[kc], bhiK, kacc[t]);
                kacc[t] = mfma16(ahi[kc], bloK, kacc[t]);
                vacc[t] = mfma16(ahi[kc], bhiV, vacc[t]);
            }
        }
        __syncthreads();
        if (h == 0) stageHalf(1);
    }

    #pragma unroll
    for (int t = 0; t < 4; ++t) {
        #pragma unroll
        for (int r = 0; r < 4; ++r) {
            {   // K: hi/lo planes
                float val = kacc[t][r];
                __bf16 hh = (__bf16)val;
                __bf16 ll = (__bf16)(val - (float)hh);
                int row = wave * 16 + quad * 4 + r;
                int lc = t * 2 + (ln >> 3);
                int sc = lc ^ (row & 7);
                int off = (row * 8 + sc) * 16 + (ln & 7) * 2;
                *(__bf16*)(WL + off) = hh;
                *(__bf16*)(WL + 8192 + off) = ll;
            }
            {   // V transposed [dv][m]
                int dvrow = t * 16 + ln;
                int m = wave * 16 + quad * 4 + r;
                int lc = m >> 3;
                int sc = lc ^ (ln & 7);
                int off = (dvrow * 8 + sc) * 16 + (m & 7) * 2;
                *(__bf16*)(WL + 16384 + off) = (__bf16)vacc[t][r];
            }
        }
    }
    __syncthreads();

    const int bh = (rt >> 4) * 8 + head;
    const int mt = rt & 15;
    const size_t tb = (size_t)(bh * 16 + mt) * 8192;
    #pragma unroll
    for (int i = 0; i < 2; ++i) {
        int c = (i * 256 + tid) * 16;
        *(uint4*)(khi_g + tb + c) = *(const uint4*)(WL + c);
        *(uint4*)(klo_g + tb + c) = *(const uint4*)(WL + 8192 + c);
        *(uint4*)(vT_g  + tb + c) = *(const uint4*)(WL + 16384 + c);
    }
}

// ---------------- attn (r10, exact): fused Q-projection + flash attention ----------------
// block = 256 thr (4 waves x 32 q-rows), BM=128, grid (128 bh FAST, 8 qt SLOW)
__global__ __launch_bounds__(256, 2) void attn_kernel(
    const float* __restrict__ X,
    const __bf16* __restrict__ Whi_t, const __bf16* __restrict__ Wlo_t,
    const unsigned char* __restrict__ khi_g, const unsigned char* __restrict__ klo_g,
    const unsigned char* __restrict__ vT_g, const unsigned long long* __restrict__ mbits,
    float* __restrict__ out)
{
    const int qt = blockIdx.y;     // 0..7
    const int bh = blockIdx.x;     // 0..127
    const int b = bh >> 3, head = bh & 7;
    const int tid = threadIdx.x, wave = tid >> 6, lane = tid & 63;
    const int quad = lane >> 4, ln = lane & 15;

    __shared__ __align__(16) unsigned char lds[49152];
    // buffers at 0 and 24576: [khi 8K][klo 8K][v 8K]; P overlays dead khi+klo (4 KB/wave)

    // ===================== Phase Q: q' = (X Wq) * SCALE2, 3-term split =====================
    f32x4 qacc[2][4];
    #pragma unroll
    for (int rg = 0; rg < 2; ++rg)
        #pragma unroll
        for (int t = 0; t < 4; ++t) qacc[rg][t] = (f32x4){0.f, 0.f, 0.f, 0.f};

    const __bf16* WhiQ = Whi_t + (size_t)head * 2048 * 8;
    const __bf16* WloQ = Wlo_t + (size_t)head * 2048 * 8;

    #pragma unroll
    for (int kc = 0; kc < 8; ++kc) {
        bf16x8 ahi[2], alo[2];
        #pragma unroll
        for (int rg = 0; rg < 2; ++rg) {
            const float* xr = X + ((size_t)b * 1024 + qt * 128 + wave * 32 + rg * 16 + ln) * 256;
            f32x4 xa = *(const f32x4*)(xr + kc * 32 + quad * 8);
            f32x4 xb = *(const f32x4*)(xr + kc * 32 + quad * 8 + 4);
            #pragma unroll
            for (int j = 0; j < 4; ++j) {
                __bf16 h0 = (__bf16)xa[j]; ahi[rg][j] = h0; alo[rg][j] = (__bf16)(xa[j] - (float)h0);
                __bf16 h1 = (__bf16)xb[j]; ahi[rg][4 + j] = h1; alo[rg][4 + j] = (__bf16)(xb[j] - (float)h1);
            }
        }
        #pragma unroll
        for (int t = 0; t < 4; ++t) {
            size_t fo = (size_t)((kc * 4 + t) * 64 + lane) * 8;
            bf16x8 bhi = *(const bf16x8*)(WhiQ + fo);
            bf16x8 blo = *(const bf16x8*)(WloQ + fo);
            #pragma unroll
            for (int rg = 0; rg < 2; ++rg) {
                qacc[rg][t] = mfma16(ahi[rg], bhi, qacc[rg][t]);
                qacc[rg][t] = mfma16(alo[rg], bhi, qacc[rg][t]);
                qacc[rg][t] = mfma16(ahi[rg], blo, qacc[rg][t]);
            }
        }
    }

    // C-layout -> A-layout transpose via LDS (per-wave region, 32 rows x 272B)
    #pragma unroll
    for (int rg = 0; rg < 2; ++rg)
        #pragma unroll
        for (int t = 0; t < 4; ++t) {
            qacc[rg][t] *= SCALE2;
            #pragma unroll
            for (int r = 0; r < 4; ++r)
                *(float*)(lds + wave * 8704 + (rg * 16 + quad * 4 + r) * 272 + (t * 16 + ln) * 4) =
                    qacc[rg][t][r];
        }
    bf16x8 qhi[2][2], qlo[2][2];
    #pragma unroll
    for (int rg = 0; rg < 2; ++rg)
        #pragma unroll
        for (int c = 0; c < 2; ++c) {
            f32x4 a0 = *(const f32x4*)(lds + wave * 8704 + (rg * 16 + ln) * 272 + c * 128 + quad * 32);
            f32x4 a1 = *(const f32x4*)(lds + wave * 8704 + (rg * 16 + ln) * 272 + c * 128 + quad * 32 + 16);
            #pragma unroll
            for (int j = 0; j < 4; ++j) {
                __bf16 h0 = (__bf16)a0[j]; qhi[rg][c][j] = h0; qlo[rg][c][j] = (__bf16)(a0[j] - (float)h0);
                __bf16 h1 = (__bf16)a1[j]; qhi[rg][c][4 + j] = h1; qlo[rg][c][4 + j] = (__bf16)(a1[j] - (float)h1);
            }
        }
    __syncthreads();

    // ===================== Phase A: flash loop over 16 m-tiles =====================
    int addrA[4][2], addrP[2];
    #pragma unroll
    for (int t = 0; t < 4; ++t)
        #pragma unroll
        for (int c = 0; c < 2; ++c)
            addrA[t][c] = (t * 16 + ln) * 128 + (((c * 4 + quad) ^ (ln & 7)) << 4);
    #pragma unroll
    for (int c = 0; c < 2; ++c)
        addrP[c] = ln * 128 + (((c * 4 + quad) ^ (ln & 7)) << 4);

    f32x4 o[2][4];
    float mrow[2][4], lrow[2][4];
    #pragma unroll
    for (int rg = 0; rg < 2; ++rg)
        #pragma unroll
        for (int t = 0; t < 4; ++t) {
            o[rg][t] = (f32x4){0.f, 0.f, 0.f, 0.f};
            mrow[rg][t] = -INFINITY; lrow[rg][t] = 0.f;   // [rg][r]
        }

    const int qrow0 = qt * 128 + wave * 32 + quad * 4;

    auto stage = [&](int mt, int bufb) {
        const unsigned char* kb = khi_g + (size_t)(bh * 16 + mt) * 8192;
        const unsigned char* lb = klo_g + (size_t)(bh * 16 + mt) * 8192;
        const unsigned char* vb = vT_g + (size_t)(bh * 16 + mt) * 8192;
        #pragma unroll
        for (int j = 0; j < 2; ++j) {
            int ch = j * 256 + wave * 64;
            load_lds16(kb + (size_t)(ch + lane) * 16, lds + bufb + ch * 16);
            load_lds16(lb + (size_t)(ch + lane) * 16, lds + bufb + 8192 + ch * 16);
            load_lds16(vb + (size_t)(ch + lane) * 16, lds + bufb + 16384 + ch * 16);
        }
    };

    auto step = [&](auto bofc, int mt) {
        constexpr int BOFF = decltype(bofc)::value;
        if (mt < 15) stage(mt + 1, 24576 - BOFF);      // prefetch next tile into other buffer

        // mask words early (independent loads)
        uint2 wm[2][4];
        #pragma unroll
        for (int rg = 0; rg < 2; ++rg)
            #pragma unroll
            for (int r = 0; r < 4; ++r)
                wm[rg][r] = *(const uint2*)((const unsigned char*)mbits +
                                            ((size_t)(qrow0 + rg * 16 + r) * 16 + mt) * 8);

        // ---- S = q' K^T (3-term, log2 domain) ----
        f32x4 s[2][4];
        #pragma unroll
        for (int rg = 0; rg < 2; ++rg)
            #pragma unroll
            for (int t = 0; t < 4; ++t) s[rg][t] = (f32x4){0.f, 0.f, 0.f, 0.f};
        #pragma unroll
        for (int t = 0; t < 4; ++t)
            #pragma unroll
            for (int c = 0; c < 2; ++c) {
                bf16x8 khi = *(const bf16x8*)(lds + BOFF + addrA[t][c]);
                bf16x8 klo = *(const bf16x8*)(lds + BOFF + 8192 + addrA[t][c]);
                #pragma unroll
                for (int rg = 0; rg < 2; ++rg) {
                    s[rg][t] = mfma16(qhi[rg][c], khi, s[rg][t]);
                    s[rg][t] = mfma16(qlo[rg][c], khi, s[rg][t]);
                    s[rg][t] = mfma16(qhi[rg][c], klo, s[rg][t]);
                }
            }

        // all waves done reading khi/klo -> safe to overlay P (keep prefetch in flight)
        asm volatile("s_waitcnt lgkmcnt(0)\n\ts_barrier" ::: "memory");

        // ---- mask + online softmax (DPP reductions) + P into dead khi/klo ----
        #pragma unroll
        for (int rg = 0; rg < 2; ++rg) {
            float pw[4][4], alpha[4];
            #pragma unroll
            for (int r = 0; r < 4; ++r) {
                float sv[4];
                #pragma unroll
                for (int t = 0; t < 4; ++t) {
                    unsigned bits = (t & 2) ? wm[rg][r].y : wm[rg][r].x;
                    float bit = (float)((bits >> ((t & 1) * 16 + ln)) & 1u);
                    sv[t] = fmaf(bit, NEGB, s[rg][t][r]);
                }
                float tm = fmaxf(fmaxf(sv[0], sv[1]), fmaxf(sv[2], sv[3]));
                tm = rowmax16(tm);
                float mn = fmaxf(mrow[rg][r], tm);
                float a = __builtin_amdgcn_exp2f(mrow[rg][r] - mn);
                float rs = 0.f;
                #pragma unroll
                for (int t = 0; t < 4; ++t) {
                    float p = __builtin_amdgcn_exp2f(sv[t] - mn);
                    pw[r][t] = p; rs += p;
                }
                rs = rowsum16(rs);
                lrow[rg][r] = lrow[rg][r] * a + rs;
                mrow[rg][r] = mn;
                alpha[r] = a;
            }
            #pragma unroll
            for (int t = 0; t < 4; ++t)
                #pragma unroll
                for (int r = 0; r < 4; ++r) o[rg][t][r] *= alpha[r];
            // P: C-layout -> A-layout (XOR-swizzled, per-wave 4 KB in dead khi/klo)
            #pragma unroll
            for (int t = 0; t < 4; ++t) {
                int lc16 = t * 32 + ((ln >> 3) << 4);
                #pragma unroll
                for (int r = 0; r < 4; ++r) {
                    int row = quad * 4 + r;
                    int addr = BOFF + wave * 4096 + rg * 2048 + row * 128 +
                               (lc16 ^ ((row & 7) << 4)) + ((ln & 7) << 1);
                    *(__bf16*)(lds + addr) = (__bf16)pw[r][t];
                }
            }
        }
        // same-wave P RAW ordering
        asm volatile("s_waitcnt lgkmcnt(0)" ::: "memory");

        // ---- O += P V ----
        #pragma unroll
        for (int c = 0; c < 2; ++c) {
            bf16x8 pa[2];
            #pragma unroll
            for (int rg = 0; rg < 2; ++rg)
                pa[rg] = *(const bf16x8*)(lds + BOFF + wave * 4096 + rg * 2048 + addrP[c]);
            #pragma unroll
            for (int t = 0; t < 4; ++t) {
                bf16x8 vb = *(const bf16x8*)(lds + BOFF + 16384 + addrA[t][c]);
                #pragma unroll
                for (int rg = 0; rg < 2; ++rg) o[rg][t] = mfma16(pa[rg], vb, o[rg][t]);
            }
        }
        __syncthreads();   // drains prefetch (vmcnt0) + P reads; next tile ready
    };

    stage(0, 0);
    __syncthreads();
    for (int mp = 0; mp < 8; ++mp) {
        step(ic<0>{}, 2 * mp);
        step(ic<24576>{}, 2 * mp + 1);
    }

    // ---- epilogue ----
    float* ob = out + (size_t)bh * 65536;
    #pragma unroll
    for (int rg = 0; rg < 2; ++rg)
        #pragma unroll
        for (int r = 0; r < 4; ++r) {
            float inv = 1.0f / lrow[rg][r];
            #pragma unroll
            for (int t = 0; t < 4; ++t)
                ob[(size_t)(qrow0 + rg * 16 + r) * 64 + t * 16 + ln] = o[rg][t][r] * inv;
        }
}

extern "C" void kernel_launch(void* const* d_in, const int* in_sizes, int n_in,
                              void* d_out, int out_size, void* d_ws, size_t ws_size,
                              hipStream_t stream) {
    const float* h    = (const float*)d_in[0];   // [16,1024,256] fp32
    const int*   mask = (const int*)d_in[1];     // [1024,1024] int32
    const float* Wq   = (const float*)d_in[2];   // [8,256,64] fp32
    const float* Wk   = (const float*)d_in[3];
    const float* Wv   = (const float*)d_in[4];
    float* out = (float*)d_out;                  // [16,8,1024,64] fp32

    unsigned char* ws = (unsigned char*)d_ws;
    unsigned char* khi_g = ws;                                   // 16 MB
    unsigned char* klo_g = ws + 16777216;                        // 16 MB
    unsigned char* vT_g  = ws + 33554432;                        // 16 MB
    __bf16* Whi_t = (__bf16*)(ws + 50331648);                    // 768 KB
    __bf16* Wlo_t = (__bf16*)(ws + 51118080);                    // 768 KB
    unsigned long long* mbits = (unsigned long long*)(ws + 51904512); // 128 KB

    prep_kernel<<<320, 256, 0, stream>>>(mask, Wq, Wk, Wv, mbits, Whi_t, Wlo_t);
    projkv_kernel<<<dim3(8, 256), 256, 0, stream>>>(h, Whi_t, Wlo_t, khi_g, klo_g, vT_g);
    attn_kernel<<<dim3(128, 8), 256, 0, stream>>>(h, Whi_t, Wlo_t, khi_g, klo_g, vT_g, mbits, out);
}

// Round 13
// 237.296 us; speedup vs baseline: 1.2558x; 1.0393x over previous
//
#include <hip/hip_runtime.h>
#include <math.h>

typedef __bf16 bf16x8 __attribute__((ext_vector_type(8)));
typedef float  f32x4  __attribute__((ext_vector_type(4)));

#define NEGB   (-1.4426950408889634e30f)   // -1e30 * log2(e)  (log2-domain mask value)
#define SCALE2 (0.18033688011112042f)      // (1/sqrt(64)) * log2(e), folded into q

template <int N> struct ic { static constexpr int value = N; };

static __device__ __forceinline__ f32x4 mfma16(bf16x8 a, bf16x8 b, f32x4 c) {
    return __builtin_amdgcn_mfma_f32_16x16x32_bf16(a, b, c, 0, 0, 0);
}

// async global->LDS, 16B per lane; lds dst = uniform base + lane*16
static __device__ __forceinline__ void load_lds16(const void* g, void* l) {
    __builtin_amdgcn_global_load_lds(
        (const __attribute__((address_space(1))) unsigned int*)g,
        (__attribute__((address_space(3))) unsigned int*)l, 16, 0, 0);
}

// DPP row_ror (within 16-lane rows) — VALU-only cross-lane, no DS pipe
template <int CTRL>
static __device__ __forceinline__ float dppf(float x) {
    int xi = __builtin_bit_cast(int, x);
    int r = __builtin_amdgcn_update_dpp(xi, xi, CTRL, 0xf, 0xf, false);
    return __builtin_bit_cast(float, r);
}
static __device__ __forceinline__ float rowmax16(float x) {
    x = fmaxf(x, dppf<0x128>(x));
    x = fmaxf(x, dppf<0x124>(x));
    x = fmaxf(x, dppf<0x122>(x));
    x = fmaxf(x, dppf<0x121>(x));
    return x;
}
static __device__ __forceinline__ float rowsum16(float x) {
    x += dppf<0x128>(x);
    x += dppf<0x124>(x);
    x += dppf<0x122>(x);
    x += dppf<0x121>(x);
    return x;
}

// ---------------- prep (r10, exact): mask -> bitmask, W -> hi/lo bf16 fragment order ------
__global__ void prep_kernel(const int* __restrict__ mask,
                            const float* __restrict__ Wq, const float* __restrict__ Wk,
                            const float* __restrict__ Wv,
                            unsigned long long* __restrict__ mbits,
                            __bf16* __restrict__ Whi_t, __bf16* __restrict__ Wlo_t)
{
    const int tid = threadIdx.x;
    if (blockIdx.x < 1024) {
        const int row = blockIdx.x, wave = tid >> 6, lane = tid & 63;
        #pragma unroll
        for (int i = 0; i < 4; ++i) {
            int word = wave * 4 + i;
            int m = mask[row * 1024 + word * 64 + lane];
            unsigned long long b = __ballot(m != 0);
            if (lane == 0) mbits[row * 16 + word] = b;
        }
    } else {
        int idx = (blockIdx.x - 1024) * 256 + tid;          // 0..49151
        int lane = idx & 63, t = (idx >> 6) & 3, kc = (idx >> 8) & 7;
        int head = (idx >> 11) & 7, mat = idx >> 14;
        int quad = lane >> 4, ln = lane & 15;
        const float* W = (mat == 0 ? Wq : (mat == 1 ? Wk : Wv)) + head * 16384;
        bf16x8 hi, lo;
        #pragma unroll
        for (int j = 0; j < 8; ++j) {
            float w = W[(kc * 32 + quad * 8 + j) * 64 + t * 16 + ln];
            __bf16 hh = (__bf16)w;
            hi[j] = hh;
            lo[j] = (__bf16)(w - (float)hh);
        }
        *(bf16x8*)(Whi_t + (size_t)idx * 8) = hi;
        *(bf16x8*)(Wlo_t + (size_t)idx * 8) = lo;
    }
}

// ---------------- projKV (r10, exact): K+V fused, W staged in LDS in TWO kc-halves --------
__global__ __launch_bounds__(256) void projkv_kernel(
    const float* __restrict__ X,
    const __bf16* __restrict__ Whi_t, const __bf16* __restrict__ Wlo_t,
    unsigned char* __restrict__ khi_g, unsigned char* __restrict__ klo_g,
    unsigned char* __restrict__ vT_g)
{
    const int head = blockIdx.x, rt = blockIdx.y;
    const int tid = threadIdx.x, wave = tid >> 6, lane = tid & 63;
    const int quad = lane >> 4, ln = lane & 15;

    __shared__ __align__(16) unsigned char WL[49152];   // [KhiK 16K][KloK 16K][VhiV 16K] per half

    const unsigned char* WhiK = (const unsigned char*)(Whi_t + ((size_t)(8 + head) * 2048) * 8);
    const unsigned char* WloK = (const unsigned char*)(Wlo_t + ((size_t)(8 + head) * 2048) * 8);
    const unsigned char* WhiV = (const unsigned char*)(Whi_t + ((size_t)(16 + head) * 2048) * 8);

    auto stageHalf = [&](int h) {
        #pragma unroll
        for (int r = 0; r < 4; ++r) {
            int seg = r * 4 + wave;                     // 0..15, wave-uniform per wave
            int gb = h * 16384 + seg * 1024 + lane * 16;
            load_lds16(WhiK + gb, WL + seg * 1024);
            load_lds16(WloK + gb, WL + 16384 + seg * 1024);
            load_lds16(WhiV + gb, WL + 32768 + seg * 1024);
        }
    };

    stageHalf(0);

    const float* xr = X + ((size_t)(rt * 64 + wave * 16 + ln)) * 256;
    bf16x8 ahi[8], alo[8];
    #pragma unroll
    for (int kc = 0; kc < 8; ++kc) {
        f32x4 xa = *(const f32x4*)(xr + kc * 32 + quad * 8);
        f32x4 xb = *(const f32x4*)(xr + kc * 32 + quad * 8 + 4);
        #pragma unroll
        for (int j = 0; j < 4; ++j) {
            __bf16 h0 = (__bf16)xa[j]; ahi[kc][j] = h0; alo[kc][j] = (__bf16)(xa[j] - (float)h0);
            __bf16 h1 = (__bf16)xb[j]; ahi[kc][4 + j] = h1; alo[kc][4 + j] = (__bf16)(xb[j] - (float)h1);
        }
    }

    f32x4 kacc[4], vacc[4];
    #pragma unroll
    for (int t = 0; t < 4; ++t) { kacc[t] = (f32x4){0.f,0.f,0.f,0.f}; vacc[t] = kacc[t]; }

    #pragma unroll
    for (int h = 0; h < 2; ++h) {
        __syncthreads();
        #pragma unroll
        for (int kcl = 0; kcl < 4; ++kcl) {
            int kc = h * 4 + kcl;
            #pragma unroll
            for (int t = 0; t < 4; ++t) {
                int fo = ((kcl * 4 + t) * 64 + lane) * 16;
                bf16x8 bhiK = *(const bf16x8*)(WL + fo);
                bf16x8 bloK = *(const bf16x8*)(WL + 16384 + fo);
                bf16x8 bhiV = *(const bf16x8*)(WL + 32768 + fo);
                kacc[t] = mfma16(ahi[kc], bhiK, kacc[t]);
                kacc[t] = mfma16(alo[kc], bhiK, kacc[t]);
                kacc[t] = mfma16(ahi[kc], bloK, kacc[t]);
                vacc[t] = mfma16(ahi[kc], bhiV, vacc[t]);
            }
        }
        __syncthreads();
        if (h == 0) stageHalf(1);
    }

    #pragma unroll
    for (int t = 0; t < 4; ++t) {
        #pragma unroll
        for (int r = 0; r < 4; ++r) {
            {   // K: hi/lo planes
                float val = kacc[t][r];
                __bf16 hh = (__bf16)val;
                __bf16 ll = (__bf16)(val - (float)hh);
                int row = wave * 16 + quad * 4 + r;
                int lc = t * 2 + (ln >> 3);
                int sc = lc ^ (row & 7);
                int off = (row * 8 + sc) * 16 + (ln & 7) * 2;
                *(__bf16*)(WL + off) = hh;
                *(__bf16*)(WL + 8192 + off) = ll;
            }
            {   // V transposed [dv][m]
                int dvrow = t * 16 + ln;
                int m = wave * 16 + quad * 4 + r;
                int lc = m >> 3;
                int sc = lc ^ (ln & 7);
                int off = (dvrow * 8 + sc) * 16 + (m & 7) * 2;
                *(__bf16*)(WL + 16384 + off) = (__bf16)vacc[t][r];
            }
        }
    }
    __syncthreads();

    const int bh = (rt >> 4) * 8 + head;
    const int mt = rt & 15;
    const size_t tb = (size_t)(bh * 16 + mt) * 8192;
    #pragma unroll
    for (int i = 0; i < 2; ++i) {
        int c = (i * 256 + tid) * 16;
        *(uint4*)(khi_g + tb + c) = *(const uint4*)(WL + c);
        *(uint4*)(klo_g + tb + c) = *(const uint4*)(WL + 8192 + c);
        *(uint4*)(vT_g  + tb + c) = *(const uint4*)(WL + 16384 + c);
    }
}

// ---------------- attn (r10, exact): fused Q-projection + flash attention ----------------
// block = 256 thr (4 waves x 32 q-rows), BM=128, grid (128 bh FAST, 8 qt SLOW)
__global__ __launch_bounds__(256, 2) void attn_kernel(
    const float* __restrict__ X,
    const __bf16* __restrict__ Whi_t, const __bf16* __restrict__ Wlo_t,
    const unsigned char* __restrict__ khi_g, const unsigned char* __restrict__ klo_g,
    const unsigned char* __restrict__ vT_g, const unsigned long long* __restrict__ mbits,
    float* __restrict__ out)
{
    const int qt = blockIdx.y;     // 0..7
    const int bh = blockIdx.x;     // 0..127
    const int b = bh >> 3, head = bh & 7;
    const int tid = threadIdx.x, wave = tid >> 6, lane = tid & 63;
    const int quad = lane >> 4, ln = lane & 15;

    __shared__ __align__(16) unsigned char lds[49152];
    // buffers at 0 and 24576: [khi 8K][klo 8K][v 8K]; P overlays dead khi+klo (4 KB/wave)

    // ===================== Phase Q: q' = (X Wq) * SCALE2, 3-term split =====================
    f32x4 qacc[2][4];
    #pragma unroll
    for (int rg = 0; rg < 2; ++rg)
        #pragma unroll
        for (int t = 0; t < 4; ++t) qacc[rg][t] = (f32x4){0.f, 0.f, 0.f, 0.f};

    const __bf16* WhiQ = Whi_t + (size_t)head * 2048 * 8;
    const __bf16* WloQ = Wlo_t + (size_t)head * 2048 * 8;

    #pragma unroll
    for (int kc = 0; kc < 8; ++kc) {
        bf16x8 ahi[2], alo[2];
        #pragma unroll
        for (int rg = 0; rg < 2; ++rg) {
            const float* xr = X + ((size_t)b * 1024 + qt * 128 + wave * 32 + rg * 16 + ln) * 256;
            f32x4 xa = *(const f32x4*)(xr + kc * 32 + quad * 8);
            f32x4 xb = *(const f32x4*)(xr + kc * 32 + quad * 8 + 4);
            #pragma unroll
            for (int j = 0; j < 4; ++j) {
                __bf16 h0 = (__bf16)xa[j]; ahi[rg][j] = h0; alo[rg][j] = (__bf16)(xa[j] - (float)h0);
                __bf16 h1 = (__bf16)xb[j]; ahi[rg][4 + j] = h1; alo[rg][4 + j] = (__bf16)(xb[j] - (float)h1);
            }
        }
        #pragma unroll
        for (int t = 0; t < 4; ++t) {
            size_t fo = (size_t)((kc * 4 + t) * 64 + lane) * 8;
            bf16x8 bhi = *(const bf16x8*)(WhiQ + fo);
            bf16x8 blo = *(const bf16x8*)(WloQ + fo);
            #pragma unroll
            for (int rg = 0; rg < 2; ++rg) {
                qacc[rg][t] = mfma16(ahi[rg], bhi, qacc[rg][t]);
                qacc[rg][t] = mfma16(alo[rg], bhi, qacc[rg][t]);
                qacc[rg][t] = mfma16(ahi[rg], blo, qacc[rg][t]);
            }
        }
    }

    // C-layout -> A-layout transpose via LDS (per-wave region, 32 rows x 272B)
    #pragma unroll
    for (int rg = 0; rg < 2; ++rg)
        #pragma unroll
        for (int t = 0; t < 4; ++t) {
            qacc[rg][t] *= SCALE2;
            #pragma unroll
            for (int r = 0; r < 4; ++r)
                *(float*)(lds + wave * 8704 + (rg * 16 + quad * 4 + r) * 272 + (t * 16 + ln) * 4) =
                    qacc[rg][t][r];
        }
    bf16x8 qhi[2][2], qlo[2][2];
    #pragma unroll
    for (int rg = 0; rg < 2; ++rg)
        #pragma unroll
        for (int c = 0; c < 2; ++c) {
            f32x4 a0 = *(const f32x4*)(lds + wave * 8704 + (rg * 16 + ln) * 272 + c * 128 + quad * 32);
            f32x4 a1 = *(const f32x4*)(lds + wave * 8704 + (rg * 16 + ln) * 272 + c * 128 + quad * 32 + 16);
            #pragma unroll
            for (int j = 0; j < 4; ++j) {
                __bf16 h0 = (__bf16)a0[j]; qhi[rg][c][j] = h0; qlo[rg][c][j] = (__bf16)(a0[j] - (float)h0);
                __bf16 h1 = (__bf16)a1[j]; qhi[rg][c][4 + j] = h1; qlo[rg][c][4 + j] = (__bf16)(a1[j] - (float)h1);
            }
        }
    __syncthreads();

    // ===================== Phase A: flash loop over 16 m-tiles =====================
    int addrA[4][2], addrP[2];
    #pragma unroll
    for (int t = 0; t < 4; ++t)
        #pragma unroll
        for (int c = 0; c < 2; ++c)
            addrA[t][c] = (t * 16 + ln) * 128 + (((c * 4 + quad) ^ (ln & 7)) << 4);
    #pragma unroll
    for (int c = 0; c < 2; ++c)
        addrP[c] = ln * 128 + (((c * 4 + quad) ^ (ln & 7)) << 4);

    f32x4 o[2][4];
    float mrow[2][4], lrow[2][4];
    #pragma unroll
    for (int rg = 0; rg < 2; ++rg)
        #pragma unroll
        for (int t = 0; t < 4; ++t) {
            o[rg][t] = (f32x4){0.f, 0.f, 0.f, 0.f};
            mrow[rg][t] = -INFINITY; lrow[rg][t] = 0.f;   // [rg][r]
        }

    const int qrow0 = qt * 128 + wave * 32 + quad * 4;

    auto stage = [&](int mt, int bufb) {
        const unsigned char* kb = khi_g + (size_t)(bh * 16 + mt) * 8192;
        const unsigned char* lb = klo_g + (size_t)(bh * 16 + mt) * 8192;
        const unsigned char* vb = vT_g + (size_t)(bh * 16 + mt) * 8192;
        #pragma unroll
        for (int j = 0; j < 2; ++j) {
            int ch = j * 256 + wave * 64;
            load_lds16(kb + (size_t)(ch + lane) * 16, lds + bufb + ch * 16);
            load_lds16(lb + (size_t)(ch + lane) * 16, lds + bufb + 8192 + ch * 16);
            load_lds16(vb + (size_t)(ch + lane) * 16, lds + bufb + 16384 + ch * 16);
        }
    };

    auto step = [&](auto bofc, int mt) {
        constexpr int BOFF = decltype(bofc)::value;
        if (mt < 15) stage(mt + 1, 24576 - BOFF);      // prefetch next tile into other buffer

        // mask words early (independent loads)
        uint2 wm[2][4];
        #pragma unroll
        for (int rg = 0; rg < 2; ++rg)
            #pragma unroll
            for (int r = 0; r < 4; ++r)
                wm[rg][r] = *(const uint2*)((const unsigned char*)mbits +
                                            ((size_t)(qrow0 + rg * 16 + r) * 16 + mt) * 8);

        // ---- S = q' K^T (3-term, log2 domain) ----
        f32x4 s[2][4];
        #pragma unroll
        for (int rg = 0; rg < 2; ++rg)
            #pragma unroll
            for (int t = 0; t < 4; ++t) s[rg][t] = (f32x4){0.f, 0.f, 0.f, 0.f};
        #pragma unroll
        for (int t = 0; t < 4; ++t)
            #pragma unroll
            for (int c = 0; c < 2; ++c) {
                bf16x8 khi = *(const bf16x8*)(lds + BOFF + addrA[t][c]);
                bf16x8 klo = *(const bf16x8*)(lds + BOFF + 8192 + addrA[t][c]);
                #pragma unroll
                for (int rg = 0; rg < 2; ++rg) {
                    s[rg][t] = mfma16(qhi[rg][c], khi, s[rg][t]);
                    s[rg][t] = mfma16(qlo[rg][c], khi, s[rg][t]);
                    s[rg][t] = mfma16(qhi[rg][c], klo, s[rg][t]);
                }
            }

        // all waves done reading khi/klo -> safe to overlay P (keep prefetch in flight)
        asm volatile("s_waitcnt lgkmcnt(0)\n\ts_barrier" ::: "memory");

        // ---- mask + online softmax (DPP reductions) + P into dead khi/klo ----
        #pragma unroll
        for (int rg = 0; rg < 2; ++rg) {
            float pw[4][4], alpha[4];
            #pragma unroll
            for (int r = 0; r < 4; ++r) {
                float sv[4];
                #pragma unroll
                for (int t = 0; t < 4; ++t) {
                    unsigned bits = (t & 2) ? wm[rg][r].y : wm[rg][r].x;
                    float bit = (float)((bits >> ((t & 1) * 16 + ln)) & 1u);
                    sv[t] = fmaf(bit, NEGB, s[rg][t][r]);
                }
                float tm = fmaxf(fmaxf(sv[0], sv[1]), fmaxf(sv[2], sv[3]));
                tm = rowmax16(tm);
                float mn = fmaxf(mrow[rg][r], tm);
                float a = __builtin_amdgcn_exp2f(mrow[rg][r] - mn);
                float rs = 0.f;
                #pragma unroll
                for (int t = 0; t < 4; ++t) {
                    float p = __builtin_amdgcn_exp2f(sv[t] - mn);
                    pw[r][t] = p; rs += p;
                }
                rs = rowsum16(rs);
                lrow[rg][r] = lrow[rg][r] * a + rs;
                mrow[rg][r] = mn;
                alpha[r] = a;
            }
            #pragma unroll
            for (int t = 0; t < 4; ++t)
                #pragma unroll
                for (int r = 0; r < 4; ++r) o[rg][t][r] *= alpha[r];
            // P: C-layout -> A-layout (XOR-swizzled, per-wave 4 KB in dead khi/klo)
            #pragma unroll
            for (int t = 0; t < 4; ++t) {
                int lc16 = t * 32 + ((ln >> 3) << 4);
                #pragma unroll
                for (int r = 0; r < 4; ++r) {
                    int row = quad * 4 + r;
                    int addr = BOFF + wave * 4096 + rg * 2048 + row * 128 +
                               (lc16 ^ ((row & 7) << 4)) + ((ln & 7) << 1);
                    *(__bf16*)(lds + addr) = (__bf16)pw[r][t];
                }
            }
        }
        // same-wave P RAW ordering
        asm volatile("s_waitcnt lgkmcnt(0)" ::: "memory");

        // ---- O += P V ----
        #pragma unroll
        for (int c = 0; c < 2; ++c) {
            bf16x8 pa[2];
            #pragma unroll
            for (int rg = 0; rg < 2; ++rg)
                pa[rg] = *(const bf16x8*)(lds + BOFF + wave * 4096 + rg * 2048 + addrP[c]);
            #pragma unroll
            for (int t = 0; t < 4; ++t) {
                bf16x8 vb = *(const bf16x8*)(lds + BOFF + 16384 + addrA[t][c]);
                #pragma unroll
                for (int rg = 0; rg < 2; ++rg) o[rg][t] = mfma16(pa[rg], vb, o[rg][t]);
            }
        }
        __syncthreads();   // drains prefetch (vmcnt0) + P reads; next tile ready
    };

    stage(0, 0);
    __syncthreads();
    for (int mp = 0; mp < 8; ++mp) {
        step(ic<0>{}, 2 * mp);
        step(ic<24576>{}, 2 * mp + 1);
    }

    // ---- epilogue ----
    float* ob = out + (size_t)bh * 65536;
    #pragma unroll
    for (int rg = 0; rg < 2; ++rg)
        #pragma unroll
        for (int r = 0; r < 4; ++r) {
            float inv = 1.0f / lrow[rg][r];
            #pragma unroll
            for (int t = 0; t < 4; ++t)
                ob[(size_t)(qrow0 + rg * 16 + r) * 64 + t * 16 + ln] = o[rg][t][r] * inv;
        }
}

extern "C" void kernel_launch(void* const* d_in, const int* in_sizes, int n_in,
                              void* d_out, int out_size, void* d_ws, size_t ws_size,
                              hipStream_t stream) {
    const float* h    = (const float*)d_in[0];   // [16,1024,256] fp32
    const int*   mask = (const int*)d_in[1];     // [1024,1024] int32
    const float* Wq   = (const float*)d_in[2];   // [8,256,64] fp32
    const float* Wk   = (const float*)d_in[3];
    const float* Wv   = (const float*)d_in[4];
    float* out = (float*)d_out;                  // [16,8,1024,64] fp32

    unsigned char* ws = (unsigned char*)d_ws;
    unsigned char* khi_g = ws;                                   // 16 MB
    unsigned char* klo_g = ws + 16777216;                        // 16 MB
    unsigned char* vT_g  = ws + 33554432;                        // 16 MB
    __bf16* Whi_t = (__bf16*)(ws + 50331648);                    // 768 KB
    __bf16* Wlo_t = (__bf16*)(ws + 51118080);                    // 768 KB
    unsigned long long* mbits = (unsigned long long*)(ws + 51904512); // 128 KB

    prep_kernel<<<1216, 256, 0, stream>>>(mask, Wq, Wk, Wv, mbits, Whi_t, Wlo_t);
    projkv_kernel<<<dim3(8, 256), 256, 0, stream>>>(h, Whi_t, Wlo_t, khi_g, klo_g, vT_g);
    attn_kernel<<<dim3(128, 8), 256, 0, stream>>>(h, Whi_t, Wlo_t, khi_g, klo_g, vT_g, mbits, out);
}